// Round 2
// baseline (4444.033 us; speedup 1.0000x reference)
//
#include <hip/hip_runtime.h>
#include <hip/hip_bf16.h>

#define NN 50000
#define EE 400000
#define EP 450000   // EE + NN self-loops

typedef __attribute__((ext_vector_type(8))) short short8;
typedef __attribute__((ext_vector_type(4))) float f32x4;

__device__ __forceinline__ float bf2f(__hip_bfloat16 b) { return __bfloat162float(b); }
__device__ __forceinline__ float us2f(unsigned short u) {
    unsigned int x = ((unsigned int)u) << 16;
    union { unsigned int i; float f; } c; c.i = x; return c.f;
}
__device__ __forceinline__ unsigned short f2bfu(float f) {   // f32 -> bf16 bits, RNE
    union { float f; unsigned int u; } c; c.f = f;
    unsigned int r = c.u + 0x7FFFu + ((c.u >> 16) & 1u);
    return (unsigned short)(r >> 16);
}

// Fragment loaders: 8 contiguous K-elements -> short8 of bf16 bits.
__device__ __forceinline__ short8 load_frag(const __hip_bfloat16* p) {
    return *(const short8*)p;
}
__device__ __forceinline__ short8 load_frag(const float* p) {
    const float4* q = (const float4*)p;
    float4 a = q[0], b = q[1];
    short8 r;
    r[0] = (short)f2bfu(a.x); r[1] = (short)f2bfu(a.y);
    r[2] = (short)f2bfu(a.z); r[3] = (short)f2bfu(a.w);
    r[4] = (short)f2bfu(b.x); r[5] = (short)f2bfu(b.y);
    r[6] = (short)f2bfu(b.z); r[7] = (short)f2bfu(b.w);
    return r;
}

// ---------------------------------------------------------------------------
// GEMM: C[m,n] = sum_k A[m,k]*B[n,k];  A:[M,K] rm, B:[NO,K] rm (f32 or bf16).
// Output bf16 [M,NO]. One 16x16 tile per wave, MFMA 16x16x32 bf16.
// grid.x = ceil(M/64) (4 waves/block stacked in M), grid.y = NO/16.
// ---------------------------------------------------------------------------
template<int K, typename TA, typename TB>
__global__ void gemm_bt(const TA* __restrict__ A,
                        const TB* __restrict__ B,
                        __hip_bfloat16* __restrict__ Cb,
                        int M, int NO) {
    int wave = threadIdx.x >> 6;
    int lane = threadIdx.x & 63;
    int m0 = blockIdx.x * 64 + wave * 16;
    int n0 = blockIdx.y * 16;
    int r = lane & 15, quad = lane >> 4;
    int am = m0 + r; if (am >= M) am = M - 1;        // clamp loads, guard stores
    const TA* arow = A + (size_t)am * K + quad * 8;
    const TB* brow = B + (size_t)(n0 + r) * K + quad * 8;
    f32x4 acc = {0.f, 0.f, 0.f, 0.f};
#pragma unroll
    for (int kk = 0; kk < K; kk += 32) {
        short8 a = load_frag(arow + kk);
        short8 b = load_frag(brow + kk);
        acc = __builtin_amdgcn_mfma_f32_16x16x32_bf16(a, b, acc, 0, 0, 0);
    }
    // C/D layout: col = lane&15 (n), row = quad*4 + i (m)
#pragma unroll
    for (int i = 0; i < 4; i++) {
        int m = m0 + quad * 4 + i;
        if (m < M) Cb[(size_t)m * NO + n0 + r] = __float2bfloat16(acc[i]);
    }
}

// ---------------------------------------------------------------------------
// Tiny GEMM for layer 3: h3[n,c] = sum_k act2[n,k]*W3[c,k]; K=128, 8 outputs.
// ---------------------------------------------------------------------------
__global__ void gemm8_kernel(const __hip_bfloat16* __restrict__ A,
                             const float* __restrict__ W,
                             __hip_bfloat16* __restrict__ Cb) {
    int gid = blockIdx.x * blockDim.x + threadIdx.x;
    if (gid >= NN * 8) return;
    int n = gid >> 3, c = gid & 7;
    const __hip_bfloat16* ap = A + (size_t)n * 128;
    const float* wp = W + c * 128;
    float acc = 0.f;
#pragma unroll 8
    for (int k = 0; k < 128; k++) acc += bf2f(ap[k]) * wp[k];
    Cb[gid] = __float2bfloat16(acc);
}

// ---------------------------------------------------------------------------
// s[n,h] = dot(h[n, h*C:...], a_s[h]); d likewise.
// ---------------------------------------------------------------------------
template<int H, int C>
__global__ void sd_kernel(const __hip_bfloat16* __restrict__ h,
                          const float* __restrict__ as_,
                          const float* __restrict__ ad_,
                          float* __restrict__ s, float* __restrict__ d) {
    int idx = blockIdx.x * blockDim.x + threadIdx.x;
    if (idx >= NN * H) return;
    int n = idx / H, hh = idx % H;
    const __hip_bfloat16* hp = h + (size_t)n * H * C + hh * C;
    const float* ap = as_ + hh * C;
    const float* bp = ad_ + hh * C;
    float ss = 0.f, dd = 0.f;
#pragma unroll 4
    for (int c = 0; c < C; c++) {
        float hv = bf2f(hp[c]);
        ss += hv * ap[c];
        dd += hv * bp[c];
    }
    s[idx] = ss; d[idx] = dd;
}

// ---------------------------------------------------------------------------
// Edge pass 1: w = exp(leaky_relu(s[src]+d[dst])); den[dst] += w  (per head)
// (max-subtraction omitted: e is O(+-10), exp safe in f32, result identical)
// ---------------------------------------------------------------------------
template<int H>
__global__ void edge_w_kernel(const int* __restrict__ ei,
                              const float* __restrict__ s, const float* __restrict__ d,
                              float* __restrict__ w, float* __restrict__ den) {
    int idx = blockIdx.x * blockDim.x + threadIdx.x;
    if (idx >= EP * H) return;
    int e = idx / H, hh = idx - e * H;
    int src, dst;
    if (e < EE) { src = ei[e]; dst = ei[EE + e]; } else { src = dst = e - EE; }
    float x = s[src * H + hh] + d[dst * H + hh];
    x = x > 0.f ? x : 0.2f * x;
    float ww = __expf(x);
    w[idx] = ww;
    atomicAdd(&den[dst * H + hh], ww);
}

// ---------------------------------------------------------------------------
// Edge pass 2: out[dst, c] += (w/den[dst]) * h[src, c]   4 channels/thread
// ---------------------------------------------------------------------------
template<int H, int C>
__global__ void scatter_kernel(const int* __restrict__ ei,
                               const __hip_bfloat16* __restrict__ h,
                               const float* __restrict__ w, const float* __restrict__ den,
                               float* __restrict__ out) {
    constexpr int HC = H * C;
    constexpr int TPE = HC / 4;            // threads per edge (pow2)
    int gid = blockIdx.x * blockDim.x + threadIdx.x;
    if (gid >= EP * TPE) return;
    int e = gid / TPE;
    int t = gid - e * TPE;
    int src, dst;
    if (e < EE) { src = ei[e]; dst = ei[EE + e]; } else { src = dst = e - EE; }
    int c0 = t * 4;
    int hh = c0 / C;
    float alpha = w[e * H + hh] / den[dst * H + hh];
    const unsigned short* hp = (const unsigned short*)(h + (size_t)src * HC + c0);
    float* op = out + (size_t)dst * HC + c0;
    ushort4 hv = *(const ushort4*)hp;
    atomicAdd(op + 0, alpha * us2f(hv.x));
    atomicAdd(op + 1, alpha * us2f(hv.y));
    atomicAdd(op + 2, alpha * us2f(hv.z));
    atomicAdd(op + 3, alpha * us2f(hv.w));
}

// ---------------------------------------------------------------------------
// act = elu(out + b), stored bf16
// ---------------------------------------------------------------------------
template<int HC>
__global__ void act_kernel(const float* __restrict__ out,
                           const float* __restrict__ b,
                           __hip_bfloat16* __restrict__ act) {
    int i = blockIdx.x * blockDim.x + threadIdx.x;
    if (i >= NN * HC) return;
    int c = i & (HC - 1);
    float v = out[i] + b[c];
    v = v > 0.f ? v : (__expf(v) - 1.0f);
    act[i] = __float2bfloat16(v);
}

// ---------------------------------------------------------------------------
// Final edge MLP: z[19] = [h3[src], h3[dst], ea, yr, qt] -> fc1(relu) -> fc2
// ---------------------------------------------------------------------------
__global__ void mlp_kernel(const int* __restrict__ ei,
                           const __hip_bfloat16* __restrict__ act3,
                           const float* __restrict__ ea,
                           const float* __restrict__ yr,
                           const float* __restrict__ qt,
                           const float* __restrict__ fc1w,
                           const float* __restrict__ fc1b,
                           const float* __restrict__ fc2w,
                           const float* __restrict__ fc2b,
                           float* __restrict__ outp) {
    __shared__ float w1[16 * 19], b1s[16], w2[16];
    for (int i = threadIdx.x; i < 16 * 19; i += blockDim.x) w1[i] = fc1w[i];
    if (threadIdx.x < 16) {
        b1s[threadIdx.x] = fc1b[threadIdx.x];
        w2[threadIdx.x] = fc2w[threadIdx.x];
    }
    __syncthreads();
    int e = blockIdx.x * blockDim.x + threadIdx.x;
    if (e >= EE) return;
    int src = ei[e], dst = ei[EE + e];
    float z[19];
#pragma unroll
    for (int i = 0; i < 8; i++) z[i] = bf2f(act3[src * 8 + i]);
#pragma unroll
    for (int i = 0; i < 8; i++) z[8 + i] = bf2f(act3[dst * 8 + i]);
    z[16] = ea[e]; z[17] = yr[e]; z[18] = qt[e];
    float acc2 = fc2b[0];
#pragma unroll
    for (int j = 0; j < 16; j++) {
        float a = b1s[j];
#pragma unroll
        for (int i = 0; i < 19; i++) a += z[i] * w1[j * 19 + i];
        a = a > 0.f ? a : 0.f;
        acc2 += a * w2[j];
    }
    outp[e] = acc2;
}

// ---------------------------------------------------------------------------
extern "C" void kernel_launch(void* const* d_in, const int* in_sizes, int n_in,
                              void* d_out, int out_size, void* d_ws, size_t ws_size,
                              hipStream_t stream) {
    const float* x    = (const float*)d_in[0];
    const int*   ei   = (const int*)d_in[1];
    const float* ea   = (const float*)d_in[2];
    const float* yr   = (const float*)d_in[3];
    const float* qt   = (const float*)d_in[4];
    const float* W1   = (const float*)d_in[5];
    const float* a1s  = (const float*)d_in[6];
    const float* a1d  = (const float*)d_in[7];
    const float* b1   = (const float*)d_in[8];
    const float* W2   = (const float*)d_in[9];
    const float* a2s  = (const float*)d_in[10];
    const float* a2d  = (const float*)d_in[11];
    const float* b2   = (const float*)d_in[12];
    const float* W3   = (const float*)d_in[13];
    const float* a3s  = (const float*)d_in[14];
    const float* a3d  = (const float*)d_in[15];
    const float* b3   = (const float*)d_in[16];
    const float* fc1w = (const float*)d_in[17];
    const float* fc1b = (const float*)d_in[18];
    const float* fc2w = (const float*)d_in[19];
    const float* fc2b = (const float*)d_in[20];
    float* outp = (float*)d_out;

    char* ws = (char*)d_ws;
    __hip_bfloat16* h_buf   = (__hip_bfloat16*)(ws);                 // N*512 bf16  (51.2 MB)
    __hip_bfloat16* act_buf = (__hip_bfloat16*)(ws + 51200000);      // N*512 bf16  (51.2 MB)
    float* out_buf = (float*)(ws + 102400000);                       // N*512 f32   (102.4 MB)
    float* s_buf   = (float*)(ws + 204800000);                       // N*4 f32
    float* d_buf   = (float*)(ws + 205600000);                       // N*4 f32
    float* den_buf = (float*)(ws + 206400000);                       // N*4 f32
    float* w_buf   = (float*)(ws + 207200000);                       // EP*4 f32 (7.2 MB)

    // ---- Layer 1: 128 -> 4 heads x 128 ----
    gemm_bt<128, float, float><<<dim3((NN + 63) / 64, 512 / 16), 256, 0, stream>>>(x, W1, h_buf, NN, 512);
    sd_kernel<4, 128><<<(NN * 4 + 255) / 256, 256, 0, stream>>>(h_buf, a1s, a1d, s_buf, d_buf);
    hipMemsetAsync(den_buf, 0, NN * 4 * sizeof(float), stream);
    hipMemsetAsync(out_buf, 0, (size_t)NN * 512 * sizeof(float), stream);
    edge_w_kernel<4><<<(EP * 4 + 255) / 256, 256, 0, stream>>>(ei, s_buf, d_buf, w_buf, den_buf);
    scatter_kernel<4, 128><<<(EP * 128 + 255) / 256, 256, 0, stream>>>(ei, h_buf, w_buf, den_buf, out_buf);
    act_kernel<512><<<(NN * 512 + 255) / 256, 256, 0, stream>>>(out_buf, b1, act_buf);

    // ---- Layer 2: 512 -> 4 heads x 32 ----
    gemm_bt<512, __hip_bfloat16, float><<<dim3((NN + 63) / 64, 128 / 16), 256, 0, stream>>>(act_buf, W2, h_buf, NN, 128);
    sd_kernel<4, 32><<<(NN * 4 + 255) / 256, 256, 0, stream>>>(h_buf, a2s, a2d, s_buf, d_buf);
    hipMemsetAsync(den_buf, 0, NN * 4 * sizeof(float), stream);
    hipMemsetAsync(out_buf, 0, (size_t)NN * 128 * sizeof(float), stream);
    edge_w_kernel<4><<<(EP * 4 + 255) / 256, 256, 0, stream>>>(ei, s_buf, d_buf, w_buf, den_buf);
    scatter_kernel<4, 32><<<(EP * 32 + 255) / 256, 256, 0, stream>>>(ei, h_buf, w_buf, den_buf, out_buf);
    act_kernel<128><<<(NN * 128 + 255) / 256, 256, 0, stream>>>(out_buf, b2, act_buf);

    // ---- Layer 3: 128 -> 1 head x 8 ----
    gemm8_kernel<<<(NN * 8 + 255) / 256, 256, 0, stream>>>(act_buf, W3, h_buf);
    sd_kernel<1, 8><<<(NN + 255) / 256, 256, 0, stream>>>(h_buf, a3s, a3d, s_buf, d_buf);
    hipMemsetAsync(den_buf, 0, NN * sizeof(float), stream);
    hipMemsetAsync(out_buf, 0, (size_t)NN * 8 * sizeof(float), stream);
    edge_w_kernel<1><<<(EP + 255) / 256, 256, 0, stream>>>(ei, s_buf, d_buf, w_buf, den_buf);
    scatter_kernel<1, 8><<<(EP * 2 + 255) / 256, 256, 0, stream>>>(ei, h_buf, w_buf, den_buf, out_buf);
    act_kernel<8><<<(NN * 8 + 255) / 256, 256, 0, stream>>>(out_buf, b3, act_buf);

    // ---- Final edge MLP ----
    mlp_kernel<<<(EE + 255) / 256, 256, 0, stream>>>(ei, act_buf, ea, yr, qt,
                                                     fc1w, fc1b, fc2w, fc2b, outp);
}

// Round 3
// 803.702 us; speedup vs baseline: 5.5295x; 5.5295x over previous
//
#include <hip/hip_runtime.h>
#include <hip/hip_bf16.h>

#define NN 50000
#define EE 400000
#define EP 450000   // EE + NN self-loops

typedef __attribute__((ext_vector_type(8))) short short8;
typedef __attribute__((ext_vector_type(4))) float f32x4;

__device__ __forceinline__ float bf2f(__hip_bfloat16 b) { return __bfloat162float(b); }
__device__ __forceinline__ float us2f(unsigned short u) {
    unsigned int x = ((unsigned int)u) << 16;
    union { unsigned int i; float f; } c; c.i = x; return c.f;
}
__device__ __forceinline__ unsigned short f2bfu(float f) {   // f32 -> bf16 bits, RNE
    union { float f; unsigned int u; } c; c.f = f;
    unsigned int r = c.u + 0x7FFFu + ((c.u >> 16) & 1u);
    return (unsigned short)(r >> 16);
}

// Fragment loaders: 8 contiguous K-elements -> short8 of bf16 bits.
__device__ __forceinline__ short8 load_frag(const __hip_bfloat16* p) {
    return *(const short8*)p;
}
__device__ __forceinline__ short8 load_frag(const float* p) {
    const float4* q = (const float4*)p;
    float4 a = q[0], b = q[1];
    short8 r;
    r[0] = (short)f2bfu(a.x); r[1] = (short)f2bfu(a.y);
    r[2] = (short)f2bfu(a.z); r[3] = (short)f2bfu(a.w);
    r[4] = (short)f2bfu(b.x); r[5] = (short)f2bfu(b.y);
    r[6] = (short)f2bfu(b.z); r[7] = (short)f2bfu(b.w);
    return r;
}

// ---------------------------------------------------------------------------
// GEMM: C[m,n] = sum_k A[m,k]*B[n,k];  A:[M,K] rm, B:[NO,K] rm (f32 or bf16).
// ---------------------------------------------------------------------------
template<int K, typename TA, typename TB>
__global__ void gemm_bt(const TA* __restrict__ A,
                        const TB* __restrict__ B,
                        __hip_bfloat16* __restrict__ Cb,
                        int M, int NO) {
    int wave = threadIdx.x >> 6;
    int lane = threadIdx.x & 63;
    int m0 = blockIdx.x * 64 + wave * 16;
    int n0 = blockIdx.y * 16;
    int r = lane & 15, quad = lane >> 4;
    int am = m0 + r; if (am >= M) am = M - 1;
    const TA* arow = A + (size_t)am * K + quad * 8;
    const TB* brow = B + (size_t)(n0 + r) * K + quad * 8;
    f32x4 acc = {0.f, 0.f, 0.f, 0.f};
#pragma unroll
    for (int kk = 0; kk < K; kk += 32) {
        short8 a = load_frag(arow + kk);
        short8 b = load_frag(brow + kk);
        acc = __builtin_amdgcn_mfma_f32_16x16x32_bf16(a, b, acc, 0, 0, 0);
    }
#pragma unroll
    for (int i = 0; i < 4; i++) {
        int m = m0 + quad * 4 + i;
        if (m < M) Cb[(size_t)m * NO + n0 + r] = __float2bfloat16(acc[i]);
    }
}

// ---------------------------------------------------------------------------
// Tiny GEMM for layer 3: h3[n,c] = sum_k act2[n,k]*W3[c,k]; K=128, 8 outputs.
// ---------------------------------------------------------------------------
__global__ void gemm8_kernel(const __hip_bfloat16* __restrict__ A,
                             const float* __restrict__ W,
                             __hip_bfloat16* __restrict__ Cb) {
    int gid = blockIdx.x * blockDim.x + threadIdx.x;
    if (gid >= NN * 8) return;
    int n = gid >> 3, c = gid & 7;
    const __hip_bfloat16* ap = A + (size_t)n * 128;
    const float* wp = W + c * 128;
    float acc = 0.f;
#pragma unroll 8
    for (int k = 0; k < 128; k++) acc += bf2f(ap[k]) * wp[k];
    Cb[gid] = __float2bfloat16(acc);
}

// ---------------------------------------------------------------------------
// s[n,h] = dot(h[n, h*C:...], a_s[h]); d likewise.
// ---------------------------------------------------------------------------
template<int H, int C>
__global__ void sd_kernel(const __hip_bfloat16* __restrict__ h,
                          const float* __restrict__ as_,
                          const float* __restrict__ ad_,
                          float* __restrict__ s, float* __restrict__ d) {
    int idx = blockIdx.x * blockDim.x + threadIdx.x;
    if (idx >= NN * H) return;
    int n = idx / H, hh = idx % H;
    const __hip_bfloat16* hp = h + (size_t)n * H * C + hh * C;
    const float* ap = as_ + hh * C;
    const float* bp = ad_ + hh * C;
    float ss = 0.f, dd = 0.f;
#pragma unroll 4
    for (int c = 0; c < C; c++) {
        float hv = bf2f(hp[c]);
        ss += hv * ap[c];
        dd += hv * bp[c];
    }
    s[idx] = ss; d[idx] = dd;
}

// ---------------------------------------------------------------------------
// Edge weights: w = exp(leaky_relu(s[src]+d[dst]))  — no atomics; den is
// computed in the gather (softmax normalization factors out of the sum).
// ---------------------------------------------------------------------------
template<int H>
__global__ void edge_w_kernel(const int* __restrict__ ei,
                              const float* __restrict__ s, const float* __restrict__ d,
                              float* __restrict__ w) {
    int idx = blockIdx.x * blockDim.x + threadIdx.x;
    if (idx >= EP * H) return;
    int e = idx / H, hh = idx - e * H;
    int src, dst;
    if (e < EE) { src = ei[e]; dst = ei[EE + e]; } else { src = dst = e - EE; }
    float x = s[src * H + hh] + d[dst * H + hh];
    x = x > 0.f ? x : 0.2f * x;
    w[idx] = __expf(x);
}

// ---------------------------------------------------------------------------
// CSR build: deg histogram -> single-block scan -> fill (dst-sorted edge list)
// ---------------------------------------------------------------------------
__global__ void deg_kernel(const int* __restrict__ ei, int* __restrict__ deg) {
    int e = blockIdx.x * blockDim.x + threadIdx.x;
    if (e >= EP) return;
    int dst = (e < EE) ? ei[EE + e] : e - EE;
    atomicAdd(&deg[dst], 1);
}

#define SCAN_T 1024
__global__ void scan_kernel(const int* __restrict__ deg, int* __restrict__ offsets) {
    __shared__ int part[SCAN_T];
    int t = threadIdx.x;
    constexpr int CHUNK = (NN + SCAN_T - 1) / SCAN_T;   // 49
    int lo = t * CHUNK;
    int hi = lo + CHUNK; if (hi > NN) hi = NN;
    int s = 0;
    for (int i = lo; i < hi && i < NN; i++) s += deg[i];
    part[t] = s;
    __syncthreads();
    for (int off = 1; off < SCAN_T; off <<= 1) {
        int v = (t >= off) ? part[t - off] : 0;
        __syncthreads();
        part[t] += v;
        __syncthreads();
    }
    int run = (t == 0) ? 0 : part[t - 1];
    for (int i = lo; i < hi && i < NN; i++) { offsets[i] = run; run += deg[i]; }
    if (t == SCAN_T - 1) offsets[NN] = run;
}

__global__ void fill_kernel(const int* __restrict__ ei, const int* __restrict__ offsets,
                            int* __restrict__ cursor, int2* __restrict__ elist) {
    int e = blockIdx.x * blockDim.x + threadIdx.x;
    if (e >= EP) return;
    int src, dst;
    if (e < EE) { src = ei[e]; dst = ei[EE + e]; } else { src = dst = e - EE; }
    int pos = atomicAdd(&cursor[dst], 1);
    int2 v; v.x = src; v.y = e;
    elist[offsets[dst] + pos] = v;
}

// ---------------------------------------------------------------------------
// Gather aggregation: out[n,c] = (sum_e w_e * h[src_e,c]) / (sum_e w_e)
// then + bias, ELU, store bf16. TPN threads per node, CPL channels per thread.
// ---------------------------------------------------------------------------
template<int H, int C, int CPL>
__global__ void gather_kernel(const int2* __restrict__ elist,
                              const int* __restrict__ offsets,
                              const __hip_bfloat16* __restrict__ h,
                              const float* __restrict__ w_buf,
                              const float* __restrict__ b,
                              __hip_bfloat16* __restrict__ act) {
    constexpr int HC = H * C;
    constexpr int TPN = HC / CPL;
    int gid = blockIdx.x * blockDim.x + threadIdx.x;
    if (gid >= NN * TPN) return;
    int node = gid / TPN;
    int t = gid - node * TPN;
    int c0 = t * CPL;
    int hh = c0 / C;
    int j0 = offsets[node], j1 = offsets[node + 1];
    float den = 0.f;
    float acc[CPL];
#pragma unroll
    for (int c = 0; c < CPL; c++) acc[c] = 0.f;
    const unsigned short* hb = (const unsigned short*)h;
    for (int j = j0; j < j1; j++) {
        int2 se = elist[j];
        float w = w_buf[se.y * H + hh];
        den += w;
        const unsigned short* hp = hb + (size_t)se.x * HC + c0;
        if constexpr (CPL == 8) {
            ushort4 a = *(const ushort4*)hp;
            ushort4 bb = *(const ushort4*)(hp + 4);
            acc[0] += w * us2f(a.x);  acc[1] += w * us2f(a.y);
            acc[2] += w * us2f(a.z);  acc[3] += w * us2f(a.w);
            acc[4] += w * us2f(bb.x); acc[5] += w * us2f(bb.y);
            acc[6] += w * us2f(bb.z); acc[7] += w * us2f(bb.w);
        } else {
            ushort2 a = *(const ushort2*)hp;
            acc[0] += w * us2f(a.x);
            acc[1] += w * us2f(a.y);
        }
    }
    float inv = 1.0f / den;   // deg >= 1 (self-loop), den > 0
    __hip_bfloat16* op = act + (size_t)node * HC + c0;
#pragma unroll
    for (int c = 0; c < CPL; c++) {
        float v = acc[c] * inv + b[c0 + c];
        v = v > 0.f ? v : (__expf(v) - 1.0f);
        op[c] = __float2bfloat16(v);
    }
}

// ---------------------------------------------------------------------------
// Final edge MLP: z[19] = [h3[src], h3[dst], ea, yr, qt] -> fc1(relu) -> fc2
// ---------------------------------------------------------------------------
__global__ void mlp_kernel(const int* __restrict__ ei,
                           const __hip_bfloat16* __restrict__ act3,
                           const float* __restrict__ ea,
                           const float* __restrict__ yr,
                           const float* __restrict__ qt,
                           const float* __restrict__ fc1w,
                           const float* __restrict__ fc1b,
                           const float* __restrict__ fc2w,
                           const float* __restrict__ fc2b,
                           float* __restrict__ outp) {
    __shared__ float w1[16 * 19], b1s[16], w2[16];
    for (int i = threadIdx.x; i < 16 * 19; i += blockDim.x) w1[i] = fc1w[i];
    if (threadIdx.x < 16) {
        b1s[threadIdx.x] = fc1b[threadIdx.x];
        w2[threadIdx.x] = fc2w[threadIdx.x];
    }
    __syncthreads();
    int e = blockIdx.x * blockDim.x + threadIdx.x;
    if (e >= EE) return;
    int src = ei[e], dst = ei[EE + e];
    float z[19];
#pragma unroll
    for (int i = 0; i < 8; i++) z[i] = bf2f(act3[src * 8 + i]);
#pragma unroll
    for (int i = 0; i < 8; i++) z[8 + i] = bf2f(act3[dst * 8 + i]);
    z[16] = ea[e]; z[17] = yr[e]; z[18] = qt[e];
    float acc2 = fc2b[0];
#pragma unroll
    for (int j = 0; j < 16; j++) {
        float a = b1s[j];
#pragma unroll
        for (int i = 0; i < 19; i++) a += z[i] * w1[j * 19 + i];
        a = a > 0.f ? a : 0.f;
        acc2 += a * w2[j];
    }
    outp[e] = acc2;
}

// ---------------------------------------------------------------------------
extern "C" void kernel_launch(void* const* d_in, const int* in_sizes, int n_in,
                              void* d_out, int out_size, void* d_ws, size_t ws_size,
                              hipStream_t stream) {
    const float* x    = (const float*)d_in[0];
    const int*   ei   = (const int*)d_in[1];
    const float* ea   = (const float*)d_in[2];
    const float* yr   = (const float*)d_in[3];
    const float* qt   = (const float*)d_in[4];
    const float* W1   = (const float*)d_in[5];
    const float* a1s  = (const float*)d_in[6];
    const float* a1d  = (const float*)d_in[7];
    const float* b1   = (const float*)d_in[8];
    const float* W2   = (const float*)d_in[9];
    const float* a2s  = (const float*)d_in[10];
    const float* a2d  = (const float*)d_in[11];
    const float* b2   = (const float*)d_in[12];
    const float* W3   = (const float*)d_in[13];
    const float* a3s  = (const float*)d_in[14];
    const float* a3d  = (const float*)d_in[15];
    const float* b3   = (const float*)d_in[16];
    const float* fc1w = (const float*)d_in[17];
    const float* fc1b = (const float*)d_in[18];
    const float* fc2w = (const float*)d_in[19];
    const float* fc2b = (const float*)d_in[20];
    float* outp = (float*)d_out;

    char* ws = (char*)d_ws;
    __hip_bfloat16* h_buf   = (__hip_bfloat16*)(ws);                 // N*512 bf16 (51.2 MB)
    __hip_bfloat16* act_buf = (__hip_bfloat16*)(ws + 51200000);      // N*512 bf16 (51.2 MB)
    float* s_buf   = (float*)(ws + 102400000);                       // N*4 f32
    float* d_buf   = (float*)(ws + 103200000);                       // N*4 f32
    float* w_buf   = (float*)(ws + 104000000);                       // EP*4 f32 (7.2 MB)
    int*   deg     = (int*)  (ws + 111200000);                       // N ints
    int*   offsets = (int*)  (ws + 111400000);                       // N+1 ints
    int*   cursor  = (int*)  (ws + 111600016);                       // N ints
    int2*  elist   = (int2*) (ws + 111800016);                       // EP int2 (3.6 MB)

    // ---- CSR build (shared by all 3 layers) ----
    hipMemsetAsync(deg, 0, NN * sizeof(int), stream);
    hipMemsetAsync(cursor, 0, NN * sizeof(int), stream);
    deg_kernel<<<(EP + 255) / 256, 256, 0, stream>>>(ei, deg);
    scan_kernel<<<1, SCAN_T, 0, stream>>>(deg, offsets);
    fill_kernel<<<(EP + 255) / 256, 256, 0, stream>>>(ei, offsets, cursor, elist);

    // ---- Layer 1: 128 -> 4 heads x 128 ----
    gemm_bt<128, float, float><<<dim3((NN + 63) / 64, 512 / 16), 256, 0, stream>>>(x, W1, h_buf, NN, 512);
    sd_kernel<4, 128><<<(NN * 4 + 255) / 256, 256, 0, stream>>>(h_buf, a1s, a1d, s_buf, d_buf);
    edge_w_kernel<4><<<(EP * 4 + 255) / 256, 256, 0, stream>>>(ei, s_buf, d_buf, w_buf);
    gather_kernel<4, 128, 8><<<(NN * 64 + 255) / 256, 256, 0, stream>>>(elist, offsets, h_buf, w_buf, b1, act_buf);

    // ---- Layer 2: 512 -> 4 heads x 32 ----
    gemm_bt<512, __hip_bfloat16, float><<<dim3((NN + 63) / 64, 128 / 16), 256, 0, stream>>>(act_buf, W2, h_buf, NN, 128);
    sd_kernel<4, 32><<<(NN * 4 + 255) / 256, 256, 0, stream>>>(h_buf, a2s, a2d, s_buf, d_buf);
    edge_w_kernel<4><<<(EP * 4 + 255) / 256, 256, 0, stream>>>(ei, s_buf, d_buf, w_buf);
    gather_kernel<4, 32, 2><<<(NN * 64 + 255) / 256, 256, 0, stream>>>(elist, offsets, h_buf, w_buf, b2, act_buf);

    // ---- Layer 3: 128 -> 1 head x 8 ----
    gemm8_kernel<<<(NN * 8 + 255) / 256, 256, 0, stream>>>(act_buf, W3, h_buf);
    sd_kernel<1, 8><<<(NN + 255) / 256, 256, 0, stream>>>(h_buf, a3s, a3d, s_buf, d_buf);
    edge_w_kernel<1><<<(EP + 255) / 256, 256, 0, stream>>>(ei, s_buf, d_buf, w_buf);
    gather_kernel<1, 8, 8><<<(NN + 255) / 256, 256, 0, stream>>>(elist, offsets, h_buf, w_buf, b3, act_buf);

    // ---- Final edge MLP ----
    mlp_kernel<<<(EE + 255) / 256, 256, 0, stream>>>(ei, act_buf, ea, yr, qt,
                                                     fc1w, fc1b, fc2w, fc2b, outp);
}

// Round 4
// 636.392 us; speedup vs baseline: 6.9832x; 1.2629x over previous
//
#include <hip/hip_runtime.h>
#include <hip/hip_bf16.h>

#define NN 50000
#define EE 400000
#define EP 450000   // EE + NN self-loops

typedef __attribute__((ext_vector_type(8))) short short8;
typedef __attribute__((ext_vector_type(4))) float f32x4;

__device__ __forceinline__ float bf2f(__hip_bfloat16 b) { return __bfloat162float(b); }
__device__ __forceinline__ float us2f(unsigned short u) {
    unsigned int x = ((unsigned int)u) << 16;
    union { unsigned int i; float f; } c; c.i = x; return c.f;
}
__device__ __forceinline__ unsigned short f2bfu(float f) {   // f32 -> bf16 bits, RNE
    union { float f; unsigned int u; } c; c.f = f;
    unsigned int r = c.u + 0x7FFFu + ((c.u >> 16) & 1u);
    return (unsigned short)(r >> 16);
}

// Fragment loaders: 8 contiguous K-elements -> short8 of bf16 bits.
__device__ __forceinline__ short8 load_frag(const __hip_bfloat16* p) {
    return *(const short8*)p;
}
__device__ __forceinline__ short8 load_frag(const float* p) {
    const float4* q = (const float4*)p;
    float4 a = q[0], b = q[1];
    short8 r;
    r[0] = (short)f2bfu(a.x); r[1] = (short)f2bfu(a.y);
    r[2] = (short)f2bfu(a.z); r[3] = (short)f2bfu(a.w);
    r[4] = (short)f2bfu(b.x); r[5] = (short)f2bfu(b.y);
    r[6] = (short)f2bfu(b.z); r[7] = (short)f2bfu(b.w);
    return r;
}

// ---------------------------------------------------------------------------
// Weight pre-convert: f32 [n] -> bf16 [n]
// ---------------------------------------------------------------------------
__global__ void cvt_kernel(const float* __restrict__ src, __hip_bfloat16* __restrict__ dst, int n) {
    int i = blockIdx.x * blockDim.x + threadIdx.x;
    if (i < n) dst[i] = __float2bfloat16(src[i]);
}

// ---------------------------------------------------------------------------
// A-stationary GEMM: C[m,n] = sum_k A[m,k]*Wb[n,k]; Wb bf16 [NO,K] (L2-resident).
// Each wave holds 16 A-rows' full-K fragments in registers (loaded ONCE),
// loops n-tiles completing each 16x16 output immediately. A fetched 1x.
// ---------------------------------------------------------------------------
template<int K, typename TA>
__global__ void gemm_rows(const TA* __restrict__ A,
                          const __hip_bfloat16* __restrict__ Wb,
                          __hip_bfloat16* __restrict__ Cb,
                          int M, int NO) {
    int wave = threadIdx.x >> 6;
    int lane = threadIdx.x & 63;
    int m0 = blockIdx.x * 64 + wave * 16;
    int r = lane & 15, quad = lane >> 4;
    int am = m0 + r; if (am >= M) am = M - 1;
    constexpr int NK = K / 32;
    short8 afrag[NK];
    const TA* arow = A + (size_t)am * K + quad * 8;
#pragma unroll
    for (int kk = 0; kk < NK; kk++) afrag[kk] = load_frag(arow + kk * 32);
    const __hip_bfloat16* wrow = Wb + (size_t)r * K + quad * 8;
    for (int n0 = 0; n0 < NO; n0 += 16) {
        f32x4 acc = {0.f, 0.f, 0.f, 0.f};
#pragma unroll
        for (int kk = 0; kk < NK; kk++) {
            short8 b = *(const short8*)(wrow + (size_t)n0 * K + kk * 32);
            acc = __builtin_amdgcn_mfma_f32_16x16x32_bf16(afrag[kk], b, acc, 0, 0, 0);
        }
        // C/D layout: col = lane&15 (n), row = quad*4 + i (m)
#pragma unroll
        for (int i = 0; i < 4; i++) {
            int m = m0 + quad * 4 + i;
            if (m < M) Cb[(size_t)m * NO + n0 + r] = __float2bfloat16(acc[i]);
        }
    }
}

// ---------------------------------------------------------------------------
// Tiny GEMM for layer 3: h3[n,c] = sum_k act2[n,k]*W3[c,k]; K=128, 8 outputs.
// ---------------------------------------------------------------------------
__global__ void gemm8_kernel(const __hip_bfloat16* __restrict__ A,
                             const float* __restrict__ W,
                             __hip_bfloat16* __restrict__ Cb) {
    int gid = blockIdx.x * blockDim.x + threadIdx.x;
    if (gid >= NN * 8) return;
    int n = gid >> 3, c = gid & 7;
    const __hip_bfloat16* ap = A + (size_t)n * 128;
    const float* wp = W + c * 128;
    float acc = 0.f;
#pragma unroll 8
    for (int k = 0; k < 128; k++) acc += bf2f(ap[k]) * wp[k];
    Cb[gid] = __float2bfloat16(acc);
}

// ---------------------------------------------------------------------------
// s[n,h] = dot(h[n, h*C:...], a_s[h]); d likewise.
// ---------------------------------------------------------------------------
template<int H, int C>
__global__ void sd_kernel(const __hip_bfloat16* __restrict__ h,
                          const float* __restrict__ as_,
                          const float* __restrict__ ad_,
                          float* __restrict__ s, float* __restrict__ d) {
    int idx = blockIdx.x * blockDim.x + threadIdx.x;
    if (idx >= NN * H) return;
    int n = idx / H, hh = idx % H;
    const __hip_bfloat16* hp = h + (size_t)n * H * C + hh * C;
    const float* ap = as_ + hh * C;
    const float* bp = ad_ + hh * C;
    float ss = 0.f, dd = 0.f;
#pragma unroll 4
    for (int c = 0; c < C; c++) {
        float hv = bf2f(hp[c]);
        ss += hv * ap[c];
        dd += hv * bp[c];
    }
    s[idx] = ss; d[idx] = dd;
}

// ---------------------------------------------------------------------------
// Edge weights: w = exp(leaky_relu(s[src]+d[dst]))  — no atomics; den is
// computed in the gather (softmax normalization factors out of the sum).
// ---------------------------------------------------------------------------
template<int H>
__global__ void edge_w_kernel(const int* __restrict__ ei,
                              const float* __restrict__ s, const float* __restrict__ d,
                              float* __restrict__ w) {
    int idx = blockIdx.x * blockDim.x + threadIdx.x;
    if (idx >= EP * H) return;
    int e = idx / H, hh = idx - e * H;
    int src, dst;
    if (e < EE) { src = ei[e]; dst = ei[EE + e]; } else { src = dst = e - EE; }
    float x = s[src * H + hh] + d[dst * H + hh];
    x = x > 0.f ? x : 0.2f * x;
    w[idx] = __expf(x);
}

// ---------------------------------------------------------------------------
// CSR build: deg histogram -> single-block scan -> fill (dst-sorted edge list)
// ---------------------------------------------------------------------------
__global__ void deg_kernel(const int* __restrict__ ei, int* __restrict__ deg) {
    int e = blockIdx.x * blockDim.x + threadIdx.x;
    if (e >= EP) return;
    int dst = (e < EE) ? ei[EE + e] : e - EE;
    atomicAdd(&deg[dst], 1);
}

#define SCAN_T 1024
__global__ void scan_kernel(const int* __restrict__ deg, int* __restrict__ offsets) {
    __shared__ int part[SCAN_T];
    int t = threadIdx.x;
    constexpr int CHUNK = (NN + SCAN_T - 1) / SCAN_T;   // 49
    int lo = t * CHUNK;
    int hi = lo + CHUNK; if (hi > NN) hi = NN;
    int s = 0;
    for (int i = lo; i < hi && i < NN; i++) s += deg[i];
    part[t] = s;
    __syncthreads();
    for (int off = 1; off < SCAN_T; off <<= 1) {
        int v = (t >= off) ? part[t - off] : 0;
        __syncthreads();
        part[t] += v;
        __syncthreads();
    }
    int run = (t == 0) ? 0 : part[t - 1];
    for (int i = lo; i < hi && i < NN; i++) { offsets[i] = run; run += deg[i]; }
    if (t == SCAN_T - 1) offsets[NN] = run;
}

__global__ void fill_kernel(const int* __restrict__ ei, const int* __restrict__ offsets,
                            int* __restrict__ cursor, int2* __restrict__ elist) {
    int e = blockIdx.x * blockDim.x + threadIdx.x;
    if (e >= EP) return;
    int src, dst;
    if (e < EE) { src = ei[e]; dst = ei[EE + e]; } else { src = dst = e - EE; }
    int pos = atomicAdd(&cursor[dst], 1);
    int2 v; v.x = src; v.y = e;
    elist[offsets[dst] + pos] = v;
}

// ---------------------------------------------------------------------------
// Gather aggregation: out[n,c] = (sum_e w_e * h[src_e,c]) / (sum_e w_e)
// then + bias, ELU, store bf16. TPN threads per node, CPL channels per thread.
// ---------------------------------------------------------------------------
template<int H, int C, int CPL>
__global__ void gather_kernel(const int2* __restrict__ elist,
                              const int* __restrict__ offsets,
                              const __hip_bfloat16* __restrict__ h,
                              const float* __restrict__ w_buf,
                              const float* __restrict__ b,
                              __hip_bfloat16* __restrict__ act) {
    constexpr int HC = H * C;
    constexpr int TPN = HC / CPL;
    int gid = blockIdx.x * blockDim.x + threadIdx.x;
    if (gid >= NN * TPN) return;
    int node = gid / TPN;
    int t = gid - node * TPN;
    int c0 = t * CPL;
    int hh = c0 / C;
    int j0 = offsets[node], j1 = offsets[node + 1];
    float den = 0.f;
    float acc[CPL];
#pragma unroll
    for (int c = 0; c < CPL; c++) acc[c] = 0.f;
    const unsigned short* hb = (const unsigned short*)h;
    for (int j = j0; j < j1; j++) {
        int2 se = elist[j];
        float w = w_buf[se.y * H + hh];
        den += w;
        const unsigned short* hp = hb + (size_t)se.x * HC + c0;
        if constexpr (CPL == 8) {
            ushort4 a = *(const ushort4*)hp;
            ushort4 bb = *(const ushort4*)(hp + 4);
            acc[0] += w * us2f(a.x);  acc[1] += w * us2f(a.y);
            acc[2] += w * us2f(a.z);  acc[3] += w * us2f(a.w);
            acc[4] += w * us2f(bb.x); acc[5] += w * us2f(bb.y);
            acc[6] += w * us2f(bb.z); acc[7] += w * us2f(bb.w);
        } else {
            ushort2 a = *(const ushort2*)hp;
            acc[0] += w * us2f(a.x);
            acc[1] += w * us2f(a.y);
        }
    }
    float inv = 1.0f / den;   // deg >= 1 (self-loop), den > 0
    __hip_bfloat16* op = act + (size_t)node * HC + c0;
#pragma unroll
    for (int c = 0; c < CPL; c++) {
        float v = acc[c] * inv + b[c0 + c];
        v = v > 0.f ? v : (__expf(v) - 1.0f);
        op[c] = __float2bfloat16(v);
    }
}

// ---------------------------------------------------------------------------
// Final edge MLP: z[19] = [h3[src], h3[dst], ea, yr, qt] -> fc1(relu) -> fc2
// ---------------------------------------------------------------------------
__global__ void mlp_kernel(const int* __restrict__ ei,
                           const __hip_bfloat16* __restrict__ act3,
                           const float* __restrict__ ea,
                           const float* __restrict__ yr,
                           const float* __restrict__ qt,
                           const float* __restrict__ fc1w,
                           const float* __restrict__ fc1b,
                           const float* __restrict__ fc2w,
                           const float* __restrict__ fc2b,
                           float* __restrict__ outp) {
    __shared__ float w1[16 * 19], b1s[16], w2[16];
    for (int i = threadIdx.x; i < 16 * 19; i += blockDim.x) w1[i] = fc1w[i];
    if (threadIdx.x < 16) {
        b1s[threadIdx.x] = fc1b[threadIdx.x];
        w2[threadIdx.x] = fc2w[threadIdx.x];
    }
    __syncthreads();
    int e = blockIdx.x * blockDim.x + threadIdx.x;
    if (e >= EE) return;
    int src = ei[e], dst = ei[EE + e];
    float z[19];
#pragma unroll
    for (int i = 0; i < 8; i++) z[i] = bf2f(act3[src * 8 + i]);
#pragma unroll
    for (int i = 0; i < 8; i++) z[8 + i] = bf2f(act3[dst * 8 + i]);
    z[16] = ea[e]; z[17] = yr[e]; z[18] = qt[e];
    float acc2 = fc2b[0];
#pragma unroll
    for (int j = 0; j < 16; j++) {
        float a = b1s[j];
#pragma unroll
        for (int i = 0; i < 19; i++) a += z[i] * w1[j * 19 + i];
        a = a > 0.f ? a : 0.f;
        acc2 += a * w2[j];
    }
    outp[e] = acc2;
}

// ---------------------------------------------------------------------------
extern "C" void kernel_launch(void* const* d_in, const int* in_sizes, int n_in,
                              void* d_out, int out_size, void* d_ws, size_t ws_size,
                              hipStream_t stream) {
    const float* x    = (const float*)d_in[0];
    const int*   ei   = (const int*)d_in[1];
    const float* ea   = (const float*)d_in[2];
    const float* yr   = (const float*)d_in[3];
    const float* qt   = (const float*)d_in[4];
    const float* W1   = (const float*)d_in[5];
    const float* a1s  = (const float*)d_in[6];
    const float* a1d  = (const float*)d_in[7];
    const float* b1   = (const float*)d_in[8];
    const float* W2   = (const float*)d_in[9];
    const float* a2s  = (const float*)d_in[10];
    const float* a2d  = (const float*)d_in[11];
    const float* b2   = (const float*)d_in[12];
    const float* W3   = (const float*)d_in[13];
    const float* a3s  = (const float*)d_in[14];
    const float* a3d  = (const float*)d_in[15];
    const float* b3   = (const float*)d_in[16];
    const float* fc1w = (const float*)d_in[17];
    const float* fc1b = (const float*)d_in[18];
    const float* fc2w = (const float*)d_in[19];
    const float* fc2b = (const float*)d_in[20];
    float* outp = (float*)d_out;

    char* ws = (char*)d_ws;
    __hip_bfloat16* h_buf   = (__hip_bfloat16*)(ws);                 // N*512 bf16 (51.2 MB)
    __hip_bfloat16* act_buf = (__hip_bfloat16*)(ws + 51200000);      // N*512 bf16 (51.2 MB)
    float* s_buf   = (float*)(ws + 102400000);                       // N*4 f32
    float* d_buf   = (float*)(ws + 103200000);                       // N*4 f32
    float* w_buf   = (float*)(ws + 104000000);                       // EP*4 f32 (7.2 MB)
    int*   deg     = (int*)  (ws + 111200000);                       // N ints
    int*   offsets = (int*)  (ws + 111400000);                       // N+1 ints
    int*   cursor  = (int*)  (ws + 111600016);                       // N ints
    int2*  elist   = (int2*) (ws + 111800016);                       // EP int2 (3.6 MB)
    __hip_bfloat16* w1bf = (__hip_bfloat16*)(ws + 115400016);        // 512*128 bf16
    __hip_bfloat16* w2bf = (__hip_bfloat16*)(ws + 115531088);        // 128*512 bf16

    // ---- CSR build + weight pre-convert ----
    hipMemsetAsync(deg, 0, NN * sizeof(int), stream);
    hipMemsetAsync(cursor, 0, NN * sizeof(int), stream);
    deg_kernel<<<(EP + 255) / 256, 256, 0, stream>>>(ei, deg);
    cvt_kernel<<<(65536 + 255) / 256, 256, 0, stream>>>(W1, w1bf, 512 * 128);
    cvt_kernel<<<(65536 + 255) / 256, 256, 0, stream>>>(W2, w2bf, 128 * 512);
    scan_kernel<<<1, SCAN_T, 0, stream>>>(deg, offsets);
    fill_kernel<<<(EP + 255) / 256, 256, 0, stream>>>(ei, offsets, cursor, elist);

    // ---- Layer 1: 128 -> 4 heads x 128 ----
    gemm_rows<128, float><<<(NN + 63) / 64, 256, 0, stream>>>(x, w1bf, h_buf, NN, 512);
    sd_kernel<4, 128><<<(NN * 4 + 255) / 256, 256, 0, stream>>>(h_buf, a1s, a1d, s_buf, d_buf);
    edge_w_kernel<4><<<(EP * 4 + 255) / 256, 256, 0, stream>>>(ei, s_buf, d_buf, w_buf);
    gather_kernel<4, 128, 8><<<(NN * 64 + 255) / 256, 256, 0, stream>>>(elist, offsets, h_buf, w_buf, b1, act_buf);

    // ---- Layer 2: 512 -> 4 heads x 32 ----
    gemm_rows<512, __hip_bfloat16><<<(NN + 63) / 64, 256, 0, stream>>>(act_buf, w2bf, h_buf, NN, 128);
    sd_kernel<4, 32><<<(NN * 4 + 255) / 256, 256, 0, stream>>>(h_buf, a2s, a2d, s_buf, d_buf);
    edge_w_kernel<4><<<(EP * 4 + 255) / 256, 256, 0, stream>>>(ei, s_buf, d_buf, w_buf);
    gather_kernel<4, 32, 2><<<(NN * 64 + 255) / 256, 256, 0, stream>>>(elist, offsets, h_buf, w_buf, b2, act_buf);

    // ---- Layer 3: 128 -> 1 head x 8 ----
    gemm8_kernel<<<(NN * 8 + 255) / 256, 256, 0, stream>>>(act_buf, W3, h_buf);
    sd_kernel<1, 8><<<(NN + 255) / 256, 256, 0, stream>>>(h_buf, a3s, a3d, s_buf, d_buf);
    edge_w_kernel<1><<<(EP + 255) / 256, 256, 0, stream>>>(ei, s_buf, d_buf, w_buf);
    gather_kernel<1, 8, 8><<<(NN + 255) / 256, 256, 0, stream>>>(elist, offsets, h_buf, w_buf, b3, act_buf);

    // ---- Final edge MLP ----
    mlp_kernel<<<(EE + 255) / 256, 256, 0, stream>>>(ei, act_buf, ea, yr, qt,
                                                     fc1w, fc1b, fc2w, fc2b, outp);
}

// Round 5
// 550.509 us; speedup vs baseline: 8.0726x; 1.1560x over previous
//
#include <hip/hip_runtime.h>
#include <hip/hip_bf16.h>

#define NN 50000
#define EE 400000
#define EP 450000   // EE + NN self-loops

typedef __attribute__((ext_vector_type(8))) short short8;
typedef __attribute__((ext_vector_type(4))) float f32x4;

__device__ __forceinline__ float bf2f(__hip_bfloat16 b) { return __bfloat162float(b); }
__device__ __forceinline__ float us2f(unsigned short u) {
    unsigned int x = ((unsigned int)u) << 16;
    union { unsigned int i; float f; } c; c.i = x; return c.f;
}
__device__ __forceinline__ unsigned short f2bfu(float f) {   // f32 -> bf16 bits, RNE
    union { float f; unsigned int u; } c; c.f = f;
    unsigned int r = c.u + 0x7FFFu + ((c.u >> 16) & 1u);
    return (unsigned short)(r >> 16);
}

// Fragment loaders: 8 contiguous K-elements -> short8 of bf16 bits.
__device__ __forceinline__ short8 load_frag(const __hip_bfloat16* p) {
    return *(const short8*)p;
}
__device__ __forceinline__ short8 load_frag(const float* p) {
    const float4* q = (const float4*)p;
    float4 a = q[0], b = q[1];
    short8 r;
    r[0] = (short)f2bfu(a.x); r[1] = (short)f2bfu(a.y);
    r[2] = (short)f2bfu(a.z); r[3] = (short)f2bfu(a.w);
    r[4] = (short)f2bfu(b.x); r[5] = (short)f2bfu(b.y);
    r[6] = (short)f2bfu(b.z); r[7] = (short)f2bfu(b.w);
    return r;
}

// ---------------------------------------------------------------------------
// Weight pre-convert: W1 and W2 f32 -> bf16, one kernel.
// ---------------------------------------------------------------------------
__global__ void cvt2_kernel(const float* __restrict__ W1, const float* __restrict__ W2,
                            __hip_bfloat16* __restrict__ w1b, __hip_bfloat16* __restrict__ w2b) {
    int i = blockIdx.x * blockDim.x + threadIdx.x;
    if (i < 65536) w1b[i] = __float2bfloat16(W1[i]);
    else if (i < 131072) w2b[i - 65536] = __float2bfloat16(W2[i - 65536]);
}

// ---------------------------------------------------------------------------
// A-stationary GEMM + fused attention-coefficient epilogue.
// C[m,n] = sum_k A[m,k]*Wb[n,k]; Wb bf16 [NO,K] (L2-resident).
// Each wave holds 16 A-rows' full-K fragments in registers (loaded ONCE),
// loops all n-tiles. Per head, also computes s[m,hh] = sum_c h*as, d likewise
// via per-tile FMA + butterfly reduce over the 16 r-lanes at head boundaries.
// ---------------------------------------------------------------------------
template<int K, int H, int C, typename TA>
__global__ void gemm_rows(const TA* __restrict__ A,
                          const __hip_bfloat16* __restrict__ Wb,
                          const float* __restrict__ as_, const float* __restrict__ ad_,
                          __hip_bfloat16* __restrict__ Cb,
                          float* __restrict__ s, float* __restrict__ d,
                          int M) {
    constexpr int NO = H * C;
    int wave = threadIdx.x >> 6;
    int lane = threadIdx.x & 63;
    int m0 = blockIdx.x * 64 + wave * 16;
    int r = lane & 15, quad = lane >> 4;
    int am = m0 + r; if (am >= M) am = M - 1;
    constexpr int NK = K / 32;
    short8 afrag[NK];
    const TA* arow = A + (size_t)am * K + quad * 8;
#pragma unroll
    for (int kk = 0; kk < NK; kk++) afrag[kk] = load_frag(arow + kk * 32);
    const __hip_bfloat16* wrow = Wb + (size_t)r * K + quad * 8;
    float sacc[4] = {0.f, 0.f, 0.f, 0.f};
    float dacc[4] = {0.f, 0.f, 0.f, 0.f};
    for (int n0 = 0; n0 < NO; n0 += 16) {
        f32x4 acc = {0.f, 0.f, 0.f, 0.f};
#pragma unroll
        for (int kk = 0; kk < NK; kk++) {
            short8 b = *(const short8*)(wrow + (size_t)n0 * K + kk * 32);
            acc = __builtin_amdgcn_mfma_f32_16x16x32_bf16(afrag[kk], b, acc, 0, 0, 0);
        }
        float as_v = as_[n0 + r];
        float ad_v = ad_[n0 + r];
        // C/D layout: col = lane&15 (n), row = quad*4 + i (m)
#pragma unroll
        for (int i = 0; i < 4; i++) {
            int m = m0 + quad * 4 + i;
            if (m < M) Cb[(size_t)m * NO + n0 + r] = __float2bfloat16(acc[i]);
            sacc[i] += acc[i] * as_v;
            dacc[i] += acc[i] * ad_v;
        }
        if ((n0 & (C - 16)) == C - 16) {      // head boundary: reduce over 16 r-lanes
            int hh = n0 / C;
#pragma unroll
            for (int mask = 1; mask <= 8; mask <<= 1) {
#pragma unroll
                for (int i = 0; i < 4; i++) {
                    sacc[i] += __shfl_xor(sacc[i], mask, 64);
                    dacc[i] += __shfl_xor(dacc[i], mask, 64);
                }
            }
            if (r == 0) {
#pragma unroll
                for (int i = 0; i < 4; i++) {
                    int m = m0 + quad * 4 + i;
                    if (m < M) { s[m * H + hh] = sacc[i]; d[m * H + hh] = dacc[i]; }
                }
            }
#pragma unroll
            for (int i = 0; i < 4; i++) { sacc[i] = 0.f; dacc[i] = 0.f; }
        }
    }
}

// ---------------------------------------------------------------------------
// Tiny GEMM for layer 3 + fused s/d: h3[n,c] = sum_k act2[n,k]*W3[c,k]; H=1.
// 8 lanes per node (8 | 64 so groups stay in-wave); butterfly over c-lanes.
// ---------------------------------------------------------------------------
__global__ void gemm8_kernel(const __hip_bfloat16* __restrict__ A,
                             const float* __restrict__ W,
                             const float* __restrict__ a3s, const float* __restrict__ a3d,
                             __hip_bfloat16* __restrict__ Cb,
                             float* __restrict__ s, float* __restrict__ d) {
    int gid = blockIdx.x * blockDim.x + threadIdx.x;
    if (gid >= NN * 8) return;
    int n = gid >> 3, c = gid & 7;
    const __hip_bfloat16* ap = A + (size_t)n * 128;
    const float* wp = W + c * 128;
    float acc = 0.f;
#pragma unroll 8
    for (int k = 0; k < 128; k++) acc += bf2f(ap[k]) * wp[k];
    Cb[gid] = __float2bfloat16(acc);
    float sv = acc * a3s[c];
    float dv = acc * a3d[c];
#pragma unroll
    for (int mask = 1; mask <= 4; mask <<= 1) {
        sv += __shfl_xor(sv, mask, 64);
        dv += __shfl_xor(dv, mask, 64);
    }
    if (c == 0) { s[n] = sv; d[n] = dv; }
}

// ---------------------------------------------------------------------------
// CSR build: deg histogram -> single-block scan -> fill (dst-sorted src list)
// ---------------------------------------------------------------------------
__global__ void deg_kernel(const int* __restrict__ ei, int* __restrict__ deg) {
    int e = blockIdx.x * blockDim.x + threadIdx.x;
    if (e >= EP) return;
    int dst = (e < EE) ? ei[EE + e] : e - EE;
    atomicAdd(&deg[dst], 1);
}

#define SCAN_T 1024
__global__ void scan_kernel(const int* __restrict__ deg, int* __restrict__ offsets) {
    __shared__ int part[SCAN_T];
    int t = threadIdx.x;
    constexpr int CHUNK = (NN + SCAN_T - 1) / SCAN_T;   // 49
    int lo = t * CHUNK;
    int hi = lo + CHUNK; if (hi > NN) hi = NN;
    int s = 0;
    for (int i = lo; i < hi && i < NN; i++) s += deg[i];
    part[t] = s;
    __syncthreads();
    for (int off = 1; off < SCAN_T; off <<= 1) {
        int v = (t >= off) ? part[t - off] : 0;
        __syncthreads();
        part[t] += v;
        __syncthreads();
    }
    int run = (t == 0) ? 0 : part[t - 1];
    for (int i = lo; i < hi && i < NN; i++) { offsets[i] = run; run += deg[i]; }
    if (t == SCAN_T - 1) offsets[NN] = run;
}

__global__ void fill_kernel(const int* __restrict__ ei, const int* __restrict__ offsets,
                            int* __restrict__ cursor, int* __restrict__ elist) {
    int e = blockIdx.x * blockDim.x + threadIdx.x;
    if (e >= EP) return;
    int src, dst;
    if (e < EE) { src = ei[e]; dst = ei[EE + e]; } else { src = dst = e - EE; }
    int pos = atomicAdd(&cursor[dst], 1);
    elist[offsets[dst] + pos] = src;
}

// ---------------------------------------------------------------------------
// Fused gather: w_e = exp(leaky_relu(s[src]+d[node])) computed inline;
// out[n,c] = (sum_e w_e * h[src_e,c]) / (sum_e w_e); then + bias, ELU -> bf16.
// TPN threads per node, CPL channels per thread.
// ---------------------------------------------------------------------------
template<int H, int C, int CPL>
__global__ void gather_fused(const int* __restrict__ elist,
                             const int* __restrict__ offsets,
                             const __hip_bfloat16* __restrict__ h,
                             const float* __restrict__ s, const float* __restrict__ d,
                             const float* __restrict__ b,
                             __hip_bfloat16* __restrict__ act) {
    constexpr int HC = H * C;
    constexpr int TPN = HC / CPL;
    int gid = blockIdx.x * blockDim.x + threadIdx.x;
    if (gid >= NN * TPN) return;
    int node = gid / TPN;
    int t = gid - node * TPN;
    int c0 = t * CPL;
    int hh = c0 / C;
    int j0 = offsets[node], j1 = offsets[node + 1];
    float dv = d[node * H + hh];
    float den = 0.f;
    float acc[CPL];
#pragma unroll
    for (int c = 0; c < CPL; c++) acc[c] = 0.f;
    const unsigned short* hb = (const unsigned short*)h;
    for (int j = j0; j < j1; j++) {
        int src = elist[j];
        float x = s[src * H + hh] + dv;
        x = x > 0.f ? x : 0.2f * x;
        float w = __expf(x);
        den += w;
        const unsigned short* hp = hb + (size_t)src * HC + c0;
        if constexpr (CPL == 8) {
            ushort4 a = *(const ushort4*)hp;
            ushort4 bb = *(const ushort4*)(hp + 4);
            acc[0] += w * us2f(a.x);  acc[1] += w * us2f(a.y);
            acc[2] += w * us2f(a.z);  acc[3] += w * us2f(a.w);
            acc[4] += w * us2f(bb.x); acc[5] += w * us2f(bb.y);
            acc[6] += w * us2f(bb.z); acc[7] += w * us2f(bb.w);
        } else {
            ushort2 a = *(const ushort2*)hp;
            acc[0] += w * us2f(a.x);
            acc[1] += w * us2f(a.y);
        }
    }
    float inv = 1.0f / den;   // deg >= 1 (self-loop), den > 0
    __hip_bfloat16* op = act + (size_t)node * HC + c0;
#pragma unroll
    for (int c = 0; c < CPL; c++) {
        float v = acc[c] * inv + b[c0 + c];
        v = v > 0.f ? v : (__expf(v) - 1.0f);
        op[c] = __float2bfloat16(v);
    }
}

// ---------------------------------------------------------------------------
// Final edge MLP: z[19] = [h3[src], h3[dst], ea, yr, qt] -> fc1(relu) -> fc2
// ---------------------------------------------------------------------------
__global__ void mlp_kernel(const int* __restrict__ ei,
                           const __hip_bfloat16* __restrict__ act3,
                           const float* __restrict__ ea,
                           const float* __restrict__ yr,
                           const float* __restrict__ qt,
                           const float* __restrict__ fc1w,
                           const float* __restrict__ fc1b,
                           const float* __restrict__ fc2w,
                           const float* __restrict__ fc2b,
                           float* __restrict__ outp) {
    __shared__ float w1[16 * 19], b1s[16], w2[16];
    for (int i = threadIdx.x; i < 16 * 19; i += blockDim.x) w1[i] = fc1w[i];
    if (threadIdx.x < 16) {
        b1s[threadIdx.x] = fc1b[threadIdx.x];
        w2[threadIdx.x] = fc2w[threadIdx.x];
    }
    __syncthreads();
    int e = blockIdx.x * blockDim.x + threadIdx.x;
    if (e >= EE) return;
    int src = ei[e], dst = ei[EE + e];
    float z[19];
#pragma unroll
    for (int i = 0; i < 8; i++) z[i] = bf2f(act3[src * 8 + i]);
#pragma unroll
    for (int i = 0; i < 8; i++) z[8 + i] = bf2f(act3[dst * 8 + i]);
    z[16] = ea[e]; z[17] = yr[e]; z[18] = qt[e];
    float acc2 = fc2b[0];
#pragma unroll
    for (int j = 0; j < 16; j++) {
        float a = b1s[j];
#pragma unroll
        for (int i = 0; i < 19; i++) a += z[i] * w1[j * 19 + i];
        a = a > 0.f ? a : 0.f;
        acc2 += a * w2[j];
    }
    outp[e] = acc2;
}

// ---------------------------------------------------------------------------
extern "C" void kernel_launch(void* const* d_in, const int* in_sizes, int n_in,
                              void* d_out, int out_size, void* d_ws, size_t ws_size,
                              hipStream_t stream) {
    const float* x    = (const float*)d_in[0];
    const int*   ei   = (const int*)d_in[1];
    const float* ea   = (const float*)d_in[2];
    const float* yr   = (const float*)d_in[3];
    const float* qt   = (const float*)d_in[4];
    const float* W1   = (const float*)d_in[5];
    const float* a1s  = (const float*)d_in[6];
    const float* a1d  = (const float*)d_in[7];
    const float* b1   = (const float*)d_in[8];
    const float* W2   = (const float*)d_in[9];
    const float* a2s  = (const float*)d_in[10];
    const float* a2d  = (const float*)d_in[11];
    const float* b2   = (const float*)d_in[12];
    const float* W3   = (const float*)d_in[13];
    const float* a3s  = (const float*)d_in[14];
    const float* a3d  = (const float*)d_in[15];
    const float* b3   = (const float*)d_in[16];
    const float* fc1w = (const float*)d_in[17];
    const float* fc1b = (const float*)d_in[18];
    const float* fc2w = (const float*)d_in[19];
    const float* fc2b = (const float*)d_in[20];
    float* outp = (float*)d_out;

    char* ws = (char*)d_ws;
    __hip_bfloat16* h_buf   = (__hip_bfloat16*)(ws);                 // N*512 bf16 (51.2 MB)
    __hip_bfloat16* act_buf = (__hip_bfloat16*)(ws + 51200000);      // N*512 bf16 (51.2 MB)
    float* s_buf   = (float*)(ws + 102400000);                       // N*4 f32
    float* d_buf   = (float*)(ws + 103200000);                       // N*4 f32
    int*   deg     = (int*)  (ws + 104000000);                       // N ints
    int*   cursor  = (int*)  (ws + 104200000);                       // N ints (contiguous w/ deg)
    int*   offsets = (int*)  (ws + 104400000);                       // N+1 ints
    int*   elist   = (int*)  (ws + 104600016);                       // EP ints (1.8 MB)
    __hip_bfloat16* w1bf = (__hip_bfloat16*)(ws + 106400016);        // 512*128 bf16
    __hip_bfloat16* w2bf = (__hip_bfloat16*)(ws + 106531088);        // 128*512 bf16

    // ---- CSR build + weight pre-convert ----
    hipMemsetAsync(deg, 0, 2 * NN * sizeof(int), stream);            // deg + cursor
    deg_kernel<<<(EP + 255) / 256, 256, 0, stream>>>(ei, deg);
    cvt2_kernel<<<(131072 + 255) / 256, 256, 0, stream>>>(W1, W2, w1bf, w2bf);
    scan_kernel<<<1, SCAN_T, 0, stream>>>(deg, offsets);
    fill_kernel<<<(EP + 255) / 256, 256, 0, stream>>>(ei, offsets, cursor, elist);

    // ---- Layer 1: 128 -> 4 heads x 128 ----
    gemm_rows<128, 4, 128, float><<<(NN + 63) / 64, 256, 0, stream>>>(
        x, w1bf, a1s, a1d, h_buf, s_buf, d_buf, NN);
    gather_fused<4, 128, 8><<<(NN * 64 + 255) / 256, 256, 0, stream>>>(
        elist, offsets, h_buf, s_buf, d_buf, b1, act_buf);

    // ---- Layer 2: 512 -> 4 heads x 32 ----
    gemm_rows<512, 4, 32, __hip_bfloat16><<<(NN + 63) / 64, 256, 0, stream>>>(
        act_buf, w2bf, a2s, a2d, h_buf, s_buf, d_buf, NN);
    gather_fused<4, 32, 2><<<(NN * 64 + 255) / 256, 256, 0, stream>>>(
        elist, offsets, h_buf, s_buf, d_buf, b2, act_buf);

    // ---- Layer 3: 128 -> 1 head x 8 ----
    gemm8_kernel<<<(NN * 8 + 255) / 256, 256, 0, stream>>>(
        act_buf, W3, a3s, a3d, h_buf, s_buf, d_buf);
    gather_fused<1, 8, 8><<<(NN + 255) / 256, 256, 0, stream>>>(
        elist, offsets, h_buf, s_buf, d_buf, b3, act_buf);

    // ---- Final edge MLP ----
    mlp_kernel<<<(EE + 255) / 256, 256, 0, stream>>>(ei, act_buf, ea, yr, qt,
                                                     fc1w, fc1b, fc2w, fc2b, outp);
}